// Round 1
// baseline (181.763 us; speedup 1.0000x reference)
//
#include <hip/hip_runtime.h>
#include <math.h>

#define NN 64
#define HH 256
#define MM 1025   // L/2+1
#define LL 2048

struct c64 { double re, im; };

__device__ __forceinline__ c64 cmul(c64 a, c64 b){
  return { a.re*b.re - a.im*b.im, a.re*b.im + a.im*b.re };
}
__device__ __forceinline__ c64 cdiv(c64 a, c64 b){
  double d = b.re*b.re + b.im*b.im;
  return { (a.re*b.re + a.im*b.im)/d, (a.im*b.re - a.re*b.im)/d };
}

// Kernel 1: compute k_f[h][m] (complex double) for h in [0,H), m in [0,M)
__global__ __launch_bounds__(256) void kf_kernel(
    const float* __restrict__ C_ri, const float* __restrict__ B_ri,
    const float* __restrict__ P_ri, const float* __restrict__ Q_ri,
    const float* __restrict__ w_ri, const float* __restrict__ log_dt,
    double2* __restrict__ kf)
{
  const int h = blockIdx.x;
  const int tid = threadIdx.x;
  __shared__ float2 sB[NN], sP[NN], sC[NN], sQ[NN], sW[NN];
  if (tid < NN) {
    sB[tid] = reinterpret_cast<const float2*>(B_ri)[h*NN + tid];
    sP[tid] = reinterpret_cast<const float2*>(P_ri)[h*NN + tid];
    sC[tid] = reinterpret_cast<const float2*>(C_ri)[h*NN + tid];
    sQ[tid] = reinterpret_cast<const float2*>(Q_ri)[h*NN + tid];
    sW[tid] = reinterpret_cast<const float2*>(w_ri)[h*NN + tid];
  }
  __syncthreads();
  const double dt = exp((double)log_dt[h]);

  for (int m = tid; m < MM; m += 256) {
    double t = (2.0 * M_PI / (double)LL) * (double)m;
    double st, ct;
    sincos(t, &st, &ct);
    c64 omega = { ct, -st };                    // e^{-it}
    c64 den   = { 1.0 + omega.re, omega.im };   // 1 + omega
    c64 num   = { 2.0*(1.0 - omega.re), -2.0*omega.im };
    c64 z     = cdiv(num, den);                 // 2(1-w)/(1+w)

    double r00r=0, r00i=0, r01r=0, r01i=0, r10r=0, r10i=0, r11r=0, r11i=0;
    #pragma unroll 4
    for (int n = 0; n < NN; ++n) {
      float2 wv = sW[n];
      double wre = (double)wv.x * dt, wim = (double)wv.y * dt;
      double d1r = z.re - wre, d1i = z.im - wim;   // z - w
      double d2r = z.re - wre, d2i = z.im + wim;   // z - conj(w)
      double q1 = 1.0 / (d1r*d1r + d1i*d1i);
      double q2 = 1.0 / (d2r*d2r + d2i*d2i);
      double i1r = d1r*q1, i1i = -d1i*q1;          // 1/(z-w)
      double i2r = d2r*q2, i2i = -d2i*q2;          // 1/(z-conj(w))
      // r += v*i1 + conj(v)*i2  ->  re: v.re*(i1r+i2r) + v.im*(i2i-i1i)
      //                             im: v.re*(i1i+i2i) + v.im*(i1r-i2r)
      double A  = i1r + i2r;
      double Bc = i2i - i1i;
      double Cc = i1i + i2i;
      double D  = i1r - i2r;
      float2 bv = sB[n], pv = sP[n], cv = sC[n], qv = sQ[n];
      double Br = bv.x, Bi = bv.y, Pr = pv.x, Pi = pv.y;
      double Cr = cv.x, Ci = cv.y, Qr = qv.x, Qi = qv.y;
      double v00r = Br*Cr - Bi*Ci, v00i = Br*Ci + Bi*Cr;   // B*C
      double v01r = Br*Qr - Bi*Qi, v01i = Br*Qi + Bi*Qr;   // B*Q
      double v10r = Pr*Cr - Pi*Ci, v10i = Pr*Ci + Pi*Cr;   // P*C
      double v11r = Pr*Qr - Pi*Qi, v11i = Pr*Qi + Pi*Qr;   // P*Q
      r00r += v00r*A + v00i*Bc;  r00i += v00r*Cc + v00i*D;
      r01r += v01r*A + v01i*Bc;  r01i += v01r*Cc + v01i*D;
      r10r += v10r*A + v10i*Bc;  r10i += v10r*Cc + v10i*D;
      r11r += v11r*A + v11i*Bc;  r11i += v11r*Cc + v11i*D;
    }
    r00r *= dt; r00i *= dt; r01r *= dt; r01i *= dt;
    r10r *= dt; r10i *= dt; r11r *= dt; r11i *= dt;

    c64 onep = { 1.0 + r11r, r11i };
    c64 corr = cdiv(cmul({r01r,r01i},{r10r,r10i}), onep);
    c64 kfv  = { r00r - corr.re, r00i - corr.im };
    c64 fac  = cdiv({2.0, 0.0}, den);           // 2/(1+omega)
    c64 o    = cmul(kfv, fac);
    kf[h*MM + m] = make_double2(o.re, o.im);
  }
}

// Kernel 2: k[h][l] = irfft(k_f[h], n=L)[l], direct half-spectrum DFT.
// k[l] = (1/L) * ( 2*sum_{m=0}^{1023}(re_m*cos - im_m*sin) - re_0 + (-1)^l * re_1024 )
__global__ __launch_bounds__(256) void irfft_kernel(
    const double2* __restrict__ kf, float* __restrict__ out)
{
  const int h = blockIdx.x;
  const int tid = threadIdx.x;
  __shared__ float2 tw[LL];      // (cos, sin)(2*pi*j/L), f32 (rounding is sign-random)
  __shared__ double2 skf[MM];    // f64 spectrum
  for (int j = tid; j < LL; j += 256) {
    double s, c;
    sincos((2.0 * M_PI / (double)LL) * (double)j, &s, &c);
    tw[j] = make_float2((float)c, (float)s);
  }
  for (int i = tid; i < MM; i += 256) skf[i] = kf[h*MM + i];
  __syncthreads();

  const double re0 = skf[0].x;
  const double reN = skf[MM-1].x;

  // Each thread computes l = tid+256*j (j=0..3) and the partner l+1024,
  // which shares the same twiddle up to (-1)^m.
  double S[8];
  #pragma unroll
  for (int j = 0; j < 8; ++j) S[j] = 0.0;
  int idx[4];
  #pragma unroll
  for (int j = 0; j < 4; ++j) idx[j] = 0;

  for (int m = 0; m < 1024; m += 2) {
    double2 a0 = skf[m];       // broadcast: all lanes same address
    double2 a1 = skf[m+1];
    #pragma unroll
    for (int j = 0; j < 4; ++j) {
      const int l = tid + 256*j;
      float2 t0 = tw[idx[j]];
      // m even: partner (l+1024) has identical twiddle
      S[j]   = fma(a0.x, (double)t0.x, S[j]);
      S[j]   = fma(-a0.y, (double)t0.y, S[j]);
      S[j+4] = fma(a0.x, (double)t0.x, S[j+4]);
      S[j+4] = fma(-a0.y, (double)t0.y, S[j+4]);
      idx[j] = (idx[j] + l) & (LL-1);
      float2 t1 = tw[idx[j]];
      // m odd: partner twiddle is negated
      S[j]   = fma(a1.x, (double)t1.x, S[j]);
      S[j]   = fma(-a1.y, (double)t1.y, S[j]);
      S[j+4] = fma(-a1.x, (double)t1.x, S[j+4]);
      S[j+4] = fma(a1.y, (double)t1.y, S[j+4]);
      idx[j] = (idx[j] + l) & (LL-1);
    }
  }

  #pragma unroll
  for (int j = 0; j < 8; ++j) {
    const int l = (j < 4) ? (tid + 256*j) : (tid + 256*(j-4) + 1024);
    double v = (2.0*S[j] - re0 + ((l & 1) ? -reN : reN)) * (1.0 / (double)LL);
    float fv = (float)v;
    if (!isfinite(fv)) fv = 0.0f;   // nan_to_num
    out[h*LL + l] = fv;
  }
}

extern "C" void kernel_launch(void* const* d_in, const int* in_sizes, int n_in,
                              void* d_out, int out_size, void* d_ws, size_t ws_size,
                              hipStream_t stream) {
  (void)in_sizes; (void)n_in; (void)out_size; (void)ws_size;
  const float* C_ri   = (const float*)d_in[0];
  const float* B_ri   = (const float*)d_in[1];
  const float* P_ri   = (const float*)d_in[2];
  const float* Q_ri   = (const float*)d_in[3];
  const float* w_ri   = (const float*)d_in[4];
  const float* logdt  = (const float*)d_in[5];
  double2* kf = (double2*)d_ws;    // H*M*16 = 4.2 MB scratch

  kf_kernel<<<HH, 256, 0, stream>>>(C_ri, B_ri, P_ri, Q_ri, w_ri, logdt, kf);
  irfft_kernel<<<HH, 256, 0, stream>>>(kf, (float*)d_out);
}

// Round 2
// 37.732 us; speedup vs baseline: 4.8172x; 4.8172x over previous
//
#include <hip/hip_runtime.h>
#include <math.h>

#define NN 64
#define HH 256
#define MM 1025   // L/2+1
#define LL 2048
#define INV_L (1.0f / 2048.0f)
#define PADIDX(a) ((a) + ((a) >> 4))

// ---------------------------------------------------------------------------
// Kernel 1: k_f[h][m] (complex f32, pre-scaled by 1/L) for h in [0,H), m in [0,M)
//
// Algebra: omega = e^{-it};  z = 2(1-omega)/(1+omega) = 2i*tan(t/2) = (0, 2tau)
//          2/(1+omega) = 1 + i*tau
// tau computed in f64 once per m, clamped to 1e7 (limit is tau-independent,
// clamping keeps n1*n2 within f32 range; rel. error O(|w|/tau) ~ 2e-6).
// Per-n m-independent data (v-products, w*dt) hoisted to LDS.
// ---------------------------------------------------------------------------
__global__ __launch_bounds__(256) void kf_kernel(
    const float* __restrict__ C_ri, const float* __restrict__ B_ri,
    const float* __restrict__ P_ri, const float* __restrict__ Q_ri,
    const float* __restrict__ w_ri, const float* __restrict__ log_dt,
    float2* __restrict__ kf)
{
  const int h   = blockIdx.y;
  const int bm  = blockIdx.x;     // 0..3
  const int tid = threadIdx.x;

  __shared__ float4 sW4[NN];  // (-wre, wre^2, wim, 0)
  __shared__ float4 sVa[NN];  // (v00r, v00i, v01r, v01i)
  __shared__ float4 sVb[NN];  // (v10r, v10i, v11r, v11i)

  const float dt = expf(log_dt[h]);

  if (tid < NN) {
    const float2 b = reinterpret_cast<const float2*>(B_ri)[h*NN + tid];
    const float2 c = reinterpret_cast<const float2*>(C_ri)[h*NN + tid];
    const float2 p = reinterpret_cast<const float2*>(P_ri)[h*NN + tid];
    const float2 q = reinterpret_cast<const float2*>(Q_ri)[h*NN + tid];
    const float2 w = reinterpret_cast<const float2*>(w_ri)[h*NN + tid];
    const float wre = w.x * dt, wim = w.y * dt;
    sW4[tid] = make_float4(-wre, wre*wre, wim, 0.f);
    sVa[tid] = make_float4(b.x*c.x - b.y*c.y, b.x*c.y + b.y*c.x,
                           b.x*q.x - b.y*q.y, b.x*q.y + b.y*q.x);
    sVb[tid] = make_float4(p.x*c.x - p.y*c.y, p.x*c.y + p.y*c.x,
                           p.x*q.x - p.y*q.y, p.x*q.y + p.y*q.x);
  }
  __syncthreads();

  // m = bm*256+tid covers 0..1023; thread (bm=0,tid=0) also does m=1024.
  for (int m = bm*256 + tid; m < MM; m += 1024) {
    double tt = (M_PI / (double)LL) * (double)m;   // t/2
    double sd, cd;
    sincos(tt, &sd, &cd);
    const float tau    = (float)fmin(sd / cd, 1.0e7);   // tan(t/2) >= 0
    const float twotau = 2.0f * tau;

    float r00r=0.f, r00i=0.f, r01r=0.f, r01i=0.f;
    float r10r=0.f, r10i=0.f, r11r=0.f, r11i=0.f;

    #pragma unroll 8
    for (int n = 0; n < NN; ++n) {
      const float4 W = sW4[n];                 // W.x=-wre(>0), W.y=wre^2, W.z=wim
      const float d1i = twotau - W.z;          // z - w
      const float d2i = twotau + W.z;          // z - conj(w)
      const float n1 = fmaf(d1i, d1i, W.y);
      const float n2 = fmaf(d2i, d2i, W.y);
      const float q12 = __builtin_amdgcn_rcpf(n1 * n2);
      const float q1 = n2 * q12;               // 1/n1
      const float q2 = n1 * q12;               // 1/n2
      const float A  = W.x * (q1 + q2);        // i1r + i2r
      const float D  = W.x * (q1 - q2);        // i1r - i2r
      const float t1 = d1i * q1;
      const float t2 = d2i * q2;
      const float Bc = t1 - t2;                // i2i - i1i
      const float Cc = -(t1 + t2);             // i1i + i2i
      const float4 va = sVa[n];
      const float4 vb = sVb[n];
      r00r = fmaf(va.x, A,  fmaf(va.y, Bc, r00r));
      r00i = fmaf(va.x, Cc, fmaf(va.y, D,  r00i));
      r01r = fmaf(va.z, A,  fmaf(va.w, Bc, r01r));
      r01i = fmaf(va.z, Cc, fmaf(va.w, D,  r01i));
      r10r = fmaf(vb.x, A,  fmaf(vb.y, Bc, r10r));
      r10i = fmaf(vb.x, Cc, fmaf(vb.y, D,  r10i));
      r11r = fmaf(vb.z, A,  fmaf(vb.w, Bc, r11r));
      r11i = fmaf(vb.z, Cc, fmaf(vb.w, D,  r11i));
    }
    // scale by dt
    r00r *= dt; r00i *= dt; r01r *= dt; r01i *= dt;
    r10r *= dt; r10i *= dt; r11r *= dt; r11i *= dt;

    // Woodbury: kf = r00 - r01*r10/(1+r11)
    const float opr = 1.0f + r11r, opi = r11i;
    const float numr = r01r*r10r - r01i*r10i;
    const float numi = r01r*r10i + r01i*r10r;
    const float qd = __builtin_amdgcn_rcpf(opr*opr + opi*opi);
    const float cr = (numr*opr + numi*opi) * qd;
    const float ci = (numi*opr - numr*opi) * qd;
    const float ar = r00r - cr, ai = r00i - ci;
    // * (1 + i*tau), * 1/L
    const float orr = fmaf(-ai, tau, ar);
    const float oii = fmaf( ar, tau, ai);
    kf[h*MM + m] = make_float2(orr * INV_L, oii * INV_L);
  }
}

// ---------------------------------------------------------------------------
// Kernel 2: out[h][l] = irfft(k_f[h], n=L)  via radix-2 DIF inverse FFT in LDS.
// Natural-order input, bit-reversed output position p holds x[bitrev11(p)].
// Twiddle W = e^{+2*pi*i*j/len}; arguments j/len are exact dyadic rationals,
// evaluated with v_sin_f32/v_cos_f32 (input in revolutions).
// ---------------------------------------------------------------------------
__global__ __launch_bounds__(256) void irfft_kernel(
    const float2* __restrict__ kf, float* __restrict__ out)
{
  const int h   = blockIdx.x;
  const int tid = threadIdx.x;
  __shared__ float2 X[2176];   // 2048 + pad (a + a>>4), max index 2174

  // Build hermitian spectrum (imag of DC/Nyquist dropped, as numpy irfft does)
  #pragma unroll
  for (int c = 0; c < 4; ++c) {
    const int m = tid + (c << 8);
    const float2 K = kf[h*MM + m];
    if (m == 0) {
      X[PADIDX(0)] = make_float2(K.x, 0.f);
    } else {
      X[PADIDX(m)]      = K;
      X[PADIDX(LL - m)] = make_float2(K.x, -K.y);
    }
  }
  if (tid == 0) {
    const float2 K = kf[h*MM + 1024];
    X[PADIDX(1024)] = make_float2(K.x, 0.f);
  }
  __syncthreads();

  for (int s = 11; s >= 1; --s) {
    const int half = 1 << (s - 1);
    const float invlen = 1.0f / (float)(1 << s);   // exact power of two
    #pragma unroll
    for (int c = 0; c < 4; ++c) {
      const int i  = tid + (c << 8);               // butterfly id 0..1023
      const int j  = i & (half - 1);
      const int i0 = ((i >> (s - 1)) << s) + j;
      const int i1 = i0 + half;
      const float2 u = X[PADIDX(i0)];
      const float2 v = X[PADIDX(i1)];
      const float rev = (float)j * invlen;         // in [0, 0.5), exact
      const float wc = __builtin_amdgcn_cosf(rev); // cos(2*pi*rev)
      const float ws = __builtin_amdgcn_sinf(rev); // sin(2*pi*rev)
      const float dx = u.x - v.x, dy = u.y - v.y;
      X[PADIDX(i0)] = make_float2(u.x + v.x, u.y + v.y);
      X[PADIDX(i1)] = make_float2(fmaf(dx, wc, -dy * ws),
                                  fmaf(dx, ws,  dy * wc));
    }
    __syncthreads();
  }

  // Reorder through LDS so global writes are coalesced.
  #pragma unroll
  for (int c = 0; c < 8; ++c) {
    const int n = tid + (c << 8);
    const int p = (int)(__brev((unsigned)n) >> 21);   // bitrev11
    const float vre = X[PADIDX(p)].x;                 // already scaled by 1/L
    out[h*LL + n] = isfinite(vre) ? vre : 0.0f;       // nan_to_num
  }
}

extern "C" void kernel_launch(void* const* d_in, const int* in_sizes, int n_in,
                              void* d_out, int out_size, void* d_ws, size_t ws_size,
                              hipStream_t stream) {
  (void)in_sizes; (void)n_in; (void)out_size; (void)ws_size;
  const float* C_ri  = (const float*)d_in[0];
  const float* B_ri  = (const float*)d_in[1];
  const float* P_ri  = (const float*)d_in[2];
  const float* Q_ri  = (const float*)d_in[3];
  const float* w_ri  = (const float*)d_in[4];
  const float* logdt = (const float*)d_in[5];
  float2* kf = (float2*)d_ws;    // H*M*8 = 2.1 MB scratch

  kf_kernel<<<dim3(4, HH), 256, 0, stream>>>(C_ri, B_ri, P_ri, Q_ri, w_ri, logdt, kf);
  irfft_kernel<<<HH, 256, 0, stream>>>(kf, (float*)d_out);
}

// Round 3
// 24.538 us; speedup vs baseline: 7.4074x; 1.5377x over previous
//
#include <hip/hip_runtime.h>
#include <math.h>

#define NN 64
#define HH 256
#define MM 1025   // L/2+1
#define LL 2048
#define INV_L (1.0f / 2048.0f)
#define PADIDX(a) ((a) + ((a) >> 4))

// ---------------------------------------------------------------------------
// Fused kernel: one block per h (grid 256, block 1024).
//  Phase A: thread tid computes spectrum bin m=tid (Cauchy sum + Woodbury),
//           writes it + hermitian mirror into the LDS FFT buffer.
//           Nyquist bin (m=1024) = analytic limit dt*Re(sum B*C) via shfl.
//  Phase B: 11-stage radix-2 DIF inverse FFT in LDS (1 butterfly/thread).
//  Phase C: bit-reversed read, coalesced global write.
//
// Algebra: omega=e^{-it}; z = 2(1-omega)/(1+omega) = 2i*tan(t/2);
//          2/(1+omega) = 1 + i*tan(t/2).  tau = tan(t/2) < inf for m<1024.
// ---------------------------------------------------------------------------
__global__ __launch_bounds__(1024) void fused_kernel(
    const float* __restrict__ C_ri, const float* __restrict__ B_ri,
    const float* __restrict__ P_ri, const float* __restrict__ Q_ri,
    const float* __restrict__ w_ri, const float* __restrict__ log_dt,
    float* __restrict__ out)
{
  const int h   = blockIdx.x;
  const int tid = threadIdx.x;

  __shared__ float2 X[2176];   // 2048 + pad (a + a>>4), max index 2174
  __shared__ float4 sW4[NN];   // (-wre, wre^2, wim, 0)
  __shared__ float4 sVa[NN];   // (v00r, v00i, v01r, v01i)
  __shared__ float4 sVb[NN];   // (v10r, v10i, v11r, v11i)

  const float dt = expf(log_dt[h]);

  if (tid < NN) {              // wave 0 only
    const float2 b = reinterpret_cast<const float2*>(B_ri)[h*NN + tid];
    const float2 c = reinterpret_cast<const float2*>(C_ri)[h*NN + tid];
    const float2 p = reinterpret_cast<const float2*>(P_ri)[h*NN + tid];
    const float2 q = reinterpret_cast<const float2*>(Q_ri)[h*NN + tid];
    const float2 w = reinterpret_cast<const float2*>(w_ri)[h*NN + tid];
    const float wre = w.x * dt, wim = w.y * dt;
    sW4[tid] = make_float4(-wre, wre*wre, wim, 0.f);
    const float v00r = b.x*c.x - b.y*c.y;
    sVa[tid] = make_float4(v00r, b.x*c.y + b.y*c.x,
                           b.x*q.x - b.y*q.y, b.x*q.y + b.y*q.x);
    sVb[tid] = make_float4(p.x*c.x - p.y*c.y, p.x*c.y + p.y*c.x,
                           p.x*q.x - p.y*q.y, p.x*q.y + p.y*q.x);
    // Nyquist bin: lim_{tau->inf} k_f = dt * Re(sum_n B_n C_n)
    float s = v00r;
    #pragma unroll
    for (int off = 32; off; off >>= 1) s += __shfl_xor(s, off, 64);
    if (tid == 0) X[PADIDX(1024)] = make_float2(dt * s * INV_L, 0.f);
  }
  __syncthreads();

  // ---- Phase A: one spectrum bin per thread (m = tid, 0..1023) ----
  {
    const int m = tid;
    double tt = (M_PI / (double)LL) * (double)m;    // t/2 in [0, pi/2)
    double sd, cd;
    sincos(tt, &sd, &cd);
    const float tau    = (float)(sd / cd);          // tan(t/2), finite
    const float twotau = 2.0f * tau;

    float r00r=0.f, r00i=0.f, r01r=0.f, r01i=0.f;
    float r10r=0.f, r10i=0.f, r11r=0.f, r11i=0.f;

    #pragma unroll 8
    for (int n = 0; n < NN; ++n) {
      const float4 W = sW4[n];                 // W.x=-wre(>0), W.y=wre^2, W.z=wim
      const float d1i = twotau - W.z;          // Im(z - w)
      const float d2i = twotau + W.z;          // Im(z - conj(w))
      const float n1 = fmaf(d1i, d1i, W.y);
      const float n2 = fmaf(d2i, d2i, W.y);
      const float q12 = __builtin_amdgcn_rcpf(n1 * n2);
      const float q1 = n2 * q12;               // 1/n1
      const float q2 = n1 * q12;               // 1/n2
      const float A  = W.x * (q1 + q2);        // Re(i1)+Re(i2)
      const float D  = W.x * (q1 - q2);        // Re(i1)-Re(i2)
      const float t1 = d1i * q1;
      const float t2 = d2i * q2;
      const float Bc = t1 - t2;                // Im(i2)-Im(i1)
      const float Cc = -(t1 + t2);             // Im(i1)+Im(i2)
      const float4 va = sVa[n];
      const float4 vb = sVb[n];
      r00r = fmaf(va.x, A,  fmaf(va.y, Bc, r00r));
      r00i = fmaf(va.x, Cc, fmaf(va.y, D,  r00i));
      r01r = fmaf(va.z, A,  fmaf(va.w, Bc, r01r));
      r01i = fmaf(va.z, Cc, fmaf(va.w, D,  r01i));
      r10r = fmaf(vb.x, A,  fmaf(vb.y, Bc, r10r));
      r10i = fmaf(vb.x, Cc, fmaf(vb.y, D,  r10i));
      r11r = fmaf(vb.z, A,  fmaf(vb.w, Bc, r11r));
      r11i = fmaf(vb.z, Cc, fmaf(vb.w, D,  r11i));
    }
    r00r *= dt; r00i *= dt; r01r *= dt; r01i *= dt;
    r10r *= dt; r10i *= dt; r11r *= dt; r11i *= dt;

    // Woodbury: kf = r00 - r01*r10/(1+r11)
    const float opr = 1.0f + r11r, opi = r11i;
    const float numr = r01r*r10r - r01i*r10i;
    const float numi = r01r*r10i + r01i*r10r;
    const float qd = __builtin_amdgcn_rcpf(opr*opr + opi*opi);
    const float cr = (numr*opr + numi*opi) * qd;
    const float ci = (numi*opr - numr*opi) * qd;
    const float ar = r00r - cr, ai = r00i - ci;
    // * (1 + i*tau), * 1/L
    const float orr = fmaf(-ai, tau, ar) * INV_L;
    const float oii = fmaf( ar, tau, ai) * INV_L;

    if (m == 0) {
      X[PADIDX(0)] = make_float2(orr, 0.f);           // DC imag dropped
    } else {
      X[PADIDX(m)]      = make_float2(orr, oii);
      X[PADIDX(LL - m)] = make_float2(orr, -oii);     // hermitian mirror
    }
  }
  __syncthreads();

  // ---- Phase B: radix-2 DIF inverse FFT, W = e^{+2*pi*i*j/len} ----
  for (int s = 11; s >= 1; --s) {
    const int half = 1 << (s - 1);
    const float invlen = 1.0f / (float)(1 << s);      // exact power of two
    const int i  = tid;                               // butterfly 0..1023
    const int j  = i & (half - 1);
    const int i0 = ((i >> (s - 1)) << s) + j;
    const int i1 = i0 + half;
    const float2 u = X[PADIDX(i0)];
    const float2 v = X[PADIDX(i1)];
    const float rev = (float)j * invlen;              // exact dyadic rational
    const float wc = __builtin_amdgcn_cosf(rev);      // cos(2*pi*rev)
    const float ws = __builtin_amdgcn_sinf(rev);      // sin(2*pi*rev)
    const float dx = u.x - v.x, dy = u.y - v.y;
    X[PADIDX(i0)] = make_float2(u.x + v.x, u.y + v.y);
    X[PADIDX(i1)] = make_float2(fmaf(dx, wc, -dy * ws),
                                fmaf(dx, ws,  dy * wc));
    __syncthreads();
  }

  // ---- Phase C: bit-reversed gather, coalesced store ----
  #pragma unroll
  for (int c = 0; c < 2; ++c) {
    const int n = tid + (c << 10);
    const int p = (int)(__brev((unsigned)n) >> 21);   // bitrev11
    const float v = X[PADIDX(p)].x;                   // already scaled by 1/L
    out[h*LL + n] = isfinite(v) ? v : 0.0f;           // nan_to_num
  }
}

extern "C" void kernel_launch(void* const* d_in, const int* in_sizes, int n_in,
                              void* d_out, int out_size, void* d_ws, size_t ws_size,
                              hipStream_t stream) {
  (void)in_sizes; (void)n_in; (void)out_size; (void)d_ws; (void)ws_size;
  const float* C_ri  = (const float*)d_in[0];
  const float* B_ri  = (const float*)d_in[1];
  const float* P_ri  = (const float*)d_in[2];
  const float* Q_ri  = (const float*)d_in[3];
  const float* w_ri  = (const float*)d_in[4];
  const float* logdt = (const float*)d_in[5];

  fused_kernel<<<HH, 1024, 0, stream>>>(C_ri, B_ri, P_ri, Q_ri, w_ri, logdt,
                                        (float*)d_out);
}